// Round 2
// baseline (1245.985 us; speedup 1.0000x reference)
//
#include <hip/hip_runtime.h>
#include <hip/hip_bf16.h>
#include <cstdint>

// MoE SwiGLU: B=8 S=2048 D=1024 H=2048 E=8 K=2. T=16384 tokens.
// Routed (top-2 only) bf16-MFMA implementation; gating in fp32 (selection must
// match np reference — bf16 logits would flip near-tie expert picks).
//
// R2 fix: workspace was ~256.8 MiB (likely > ws_size=256 MiB) -> GPU memory
// fault on first call. Now w2b aliases xb (dead after GEMM1), act trimmed,
// control buffers allocated first. Total ~224.5 MiB. Memsets -> zero kernels.

#define T_TOK 16384
#define DIM   1024
#define HID   2048
#define NEXP  8
#define MAX_TILES 264   // sum ceil(Ne/128) <= 32768/128 + 8

typedef __bf16 bf16;
typedef bf16  bf16x8 __attribute__((ext_vector_type(8)));
typedef bf16  bf16x4 __attribute__((ext_vector_type(4)));
typedef float f32x16 __attribute__((ext_vector_type(16)));

__device__ __forceinline__ void async_cp16(const void* g, void* l) {
  // LDS dest is wave-uniform base + lane*16 (hardware semantics); our staging
  // layout is exactly lane-contiguous per wave.
  __builtin_amdgcn_global_load_lds((const __attribute__((address_space(1))) void*)g,
                                   (__attribute__((address_space(3))) void*)l, 16, 0, 0);
}

// ---------------- zero out + control ints ----------------
__global__ __launch_bounds__(256) void zero_kernel(float4* __restrict__ out4, int n4,
                                                   int* __restrict__ ctrl) {
  const int i = blockIdx.x * 256 + threadIdx.x;
  if (i < n4) out4[i] = float4{0.f, 0.f, 0.f, 0.f};
  if (blockIdx.x == 0 && threadIdx.x < 64) ctrl[threadIdx.x] = 0;
}

// ---------------- fp32 -> bf16 convert (x, w1, w3, w2) ----------------
__global__ __launch_bounds__(256) void cvt_kernel(const float* __restrict__ in,
                                                  bf16* __restrict__ out, int n4) {
  const int i = blockIdx.x * 256 + threadIdx.x;
  if (i < n4) {
    const float4 v = ((const float4*)in)[i];
    bf16x4 o;
    o[0] = (bf16)v.x; o[1] = (bf16)v.y; o[2] = (bf16)v.z; o[3] = (bf16)v.w;
    ((bf16x4*)out)[i] = o;
  }
}

// ---------------- gating: fp32 logits, top-2, softmax ----------------
__global__ __launch_bounds__(64) void gate_kernel(const float* __restrict__ x,
                                                  const float* __restrict__ gw,
                                                  int* __restrict__ sel,
                                                  float* __restrict__ selw) {
  const int t = blockIdx.x;
  const int lane = threadIdx.x;
  const float* xr = x + (size_t)t * DIM;
  float acc[NEXP];
#pragma unroll
  for (int e = 0; e < NEXP; e++) acc[e] = 0.f;
  for (int i = lane; i < DIM; i += 64) {
    const float xv = xr[i];
#pragma unroll
    for (int e = 0; e < NEXP; e++) acc[e] += xv * gw[e * DIM + i];
  }
#pragma unroll
  for (int e = 0; e < NEXP; e++) {
#pragma unroll
    for (int m = 1; m < 64; m <<= 1) acc[e] += __shfl_xor(acc[e], m);
  }
  if (lane == 0) {
    int e0 = 0; float l0 = acc[0];
#pragma unroll
    for (int e = 1; e < NEXP; e++) if (acc[e] > l0) { l0 = acc[e]; e0 = e; }
    int e1 = -1; float l1 = -3.4e38f;
#pragma unroll
    for (int e = 0; e < NEXP; e++) if (e != e0 && acc[e] > l1) { l1 = acc[e]; e1 = e; }
    const float ex = expf(l1 - l0);            // l1 <= l0
    const float w0 = 1.f / (1.f + ex);
    sel[t * 2] = e0;  sel[t * 2 + 1] = e1;
    selw[t * 2] = w0; selw[t * 2 + 1] = 1.f - w0;
  }
}

// ---------------- per-expert counts (wave-aggregated atomics) ----------------
__global__ __launch_bounds__(256) void count_kernel(const int* __restrict__ sel,
                                                    int* __restrict__ counts) {
  const int i = blockIdx.x * 256 + threadIdx.x;   // over 2*T_TOK, exact grid
  const int lane = threadIdx.x & 63;
  const int e = sel[i];
#pragma unroll
  for (int ee = 0; ee < NEXP; ee++) {
    const unsigned long long mask = __ballot(e == ee);
    if (e == ee) {
      const int leader = __ffsll(mask) - 1;
      if (lane == leader) atomicAdd(&counts[ee], __popcll(mask));
    }
  }
}

// ---------------- segment offsets + tile map (1 thread) ----------------
__global__ void tilemap_kernel(const int* __restrict__ counts, int* __restrict__ segoff,
                               int* __restrict__ tile_e, int* __restrict__ tile_m,
                               int* __restrict__ ntiles) {
  if (threadIdx.x == 0 && blockIdx.x == 0) {
    int off = 0, nt = 0;
    for (int e = 0; e < NEXP; e++) {
      segoff[e] = off;
      const int c = counts[e];
      for (int m = 0; m < c; m += 128) { tile_e[nt] = e; tile_m[nt] = m; nt++; }
      off += c;
    }
    segoff[NEXP] = off;
    ntiles[0] = nt;
  }
}

// ---------------- fill gather lists (wave-aggregated positions) ----------------
__global__ __launch_bounds__(256) void fill_kernel(const int* __restrict__ sel,
                                                   const float* __restrict__ selw,
                                                   const int* __restrict__ segoff,
                                                   int* __restrict__ fill,
                                                   int* __restrict__ tokl,
                                                   float* __restrict__ wl) {
  const int t = blockIdx.x * 256 + threadIdx.x;   // exact grid, all lanes active
  const int lane = threadIdx.x & 63;
#pragma unroll
  for (int s = 0; s < 2; s++) {
    const int e = sel[t * 2 + s];
    const float w = selw[t * 2 + s];
    for (int ee = 0; ee < NEXP; ee++) {
      const unsigned long long mask = __ballot(e == ee);
      if (e == ee) {
        const int leader = __ffsll(mask) - 1;
        const int cnt = __popcll(mask);
        int base = 0;
        if (lane == leader) base = atomicAdd(&fill[ee], cnt);
        base = __shfl(base, leader);
        const int pos = base + __popcll(mask & ((1ull << lane) - 1ull));
        const int idx = segoff[ee] + pos;
        tokl[idx] = t;
        wl[idx] = w;
      }
    }
  }
}

// ---------------- GEMM1 + SwiGLU: act = silu(Xe@w1^T) * (Xe@w3^T) ----------------
// BM=128, BN=64 (H cols), BK=64. 4 waves: wave tile = 64 rows x 32 cols, dual-matrix.
// mfma_f32_32x32x16_bf16: A lane l holds A[m=l&31][k=(l>>5)*8+j]; B^T input same;
// C/D: col=lane&31, row=(reg&3)+8*(reg>>2)+4*(lane>>5)  [m74/m101-verified].
__global__ __launch_bounds__(256) void gemm_act_kernel(
    const bf16* __restrict__ xb, const bf16* __restrict__ w1b, const bf16* __restrict__ w3b,
    const int* __restrict__ tokl, const int* __restrict__ counts, const int* __restrict__ segoff,
    const int* __restrict__ tile_e, const int* __restrict__ tile_m, const int* __restrict__ ntiles,
    bf16* __restrict__ act) {
  const int tile = blockIdx.x;
  if (tile >= *ntiles) return;
  const int e   = tile_e[tile];
  const int m0  = tile_m[tile];
  const int n0  = blockIdx.y * 64;
  const int Ne  = counts[e];
  const int seg = segoff[e];

  __shared__ bf16 As[128 * 64];
  __shared__ bf16 Bs1[64 * 64];
  __shared__ bf16 Bs3[64 * 64];

  const int tid = threadIdx.x;
  const int lane = tid & 63;
  const int wv = tid >> 6;
  const int sr = tid >> 3;        // staging row 0..31
  const int scb = tid & 7;        // 16B col block

  const bf16* aptr[4];
#pragma unroll
  for (int i = 0; i < 4; i++) {
    int m = m0 + sr + 32 * i; if (m > Ne - 1) m = Ne - 1;   // clamp tail
    aptr[i] = xb + (size_t)tokl[seg + m] * DIM + scb * 8;
  }
  const bf16 *b1p[2], *b3p[2];
#pragma unroll
  for (int i = 0; i < 2; i++) {
    const int n = n0 + sr + 32 * i;
    b1p[i] = w1b + ((size_t)e * HID + n) * DIM + scb * 8;
    b3p[i] = w3b + ((size_t)e * HID + n) * DIM + scb * 8;
  }

  f32x16 acc1[2], acc3[2];
#pragma unroll
  for (int i = 0; i < 2; i++)
#pragma unroll
    for (int j = 0; j < 16; j++) { acc1[i][j] = 0.f; acc3[i][j] = 0.f; }

  const int lwm = (wv & 1) * 64;
  const int lwn = (wv >> 1) * 32;
  const int l31 = lane & 31;
  const int lhi = lane >> 5;

  for (int k0 = 0; k0 < DIM; k0 += 64) {
#pragma unroll
    for (int i = 0; i < 4; i++)
      async_cp16(aptr[i] + k0, (char*)As + i * 4096 + tid * 16);
#pragma unroll
    for (int i = 0; i < 2; i++) {
      async_cp16(b1p[i] + k0, (char*)Bs1 + i * 4096 + tid * 16);
      async_cp16(b3p[i] + k0, (char*)Bs3 + i * 4096 + tid * 16);
    }
    __syncthreads();
#pragma unroll
    for (int ks = 0; ks < 4; ks++) {
      const int kk = ks * 16 + lhi * 8;
      bf16x8 a0 = *(const bf16x8*)(As + (lwm + l31) * 64 + kk);
      bf16x8 a1 = *(const bf16x8*)(As + (lwm + 32 + l31) * 64 + kk);
      bf16x8 b1 = *(const bf16x8*)(Bs1 + (lwn + l31) * 64 + kk);
      bf16x8 b3 = *(const bf16x8*)(Bs3 + (lwn + l31) * 64 + kk);
      acc1[0] = __builtin_amdgcn_mfma_f32_32x32x16_bf16(a0, b1, acc1[0], 0, 0, 0);
      acc3[0] = __builtin_amdgcn_mfma_f32_32x32x16_bf16(a0, b3, acc3[0], 0, 0, 0);
      acc1[1] = __builtin_amdgcn_mfma_f32_32x32x16_bf16(a1, b1, acc1[1], 0, 0, 0);
      acc3[1] = __builtin_amdgcn_mfma_f32_32x32x16_bf16(a1, b3, acc3[1], 0, 0, 0);
    }
    __syncthreads();
  }

#pragma unroll
  for (int ms = 0; ms < 2; ms++) {
#pragma unroll
    for (int r = 0; r < 16; r++) {
      const int row = lwm + 32 * ms + (r & 3) + 8 * (r >> 2) + 4 * lhi;
      const int m = m0 + row;
      if (m < Ne) {   // guard: never write past segment into next expert
        const float h1 = acc1[ms][r];
        const float h3 = acc3[ms][r];
        const float sv = h1 / (1.f + __expf(-h1)) * h3;
        act[(size_t)(seg + m) * HID + (n0 + lwn + l31)] = (bf16)sv;
      }
    }
  }
}

// ---------------- GEMM2 + scatter: out[tok] += cw * (act @ w2^T) ----------------
// BM=128, BN=128 (D cols), BK=64. 4 waves 2x2, wave tile 64x64 (2x2 MFMA 32x32).
__global__ __launch_bounds__(256) void gemm_out_kernel(
    const bf16* __restrict__ act, const bf16* __restrict__ w2b,
    const int* __restrict__ tokl, const float* __restrict__ wl,
    const int* __restrict__ counts, const int* __restrict__ segoff,
    const int* __restrict__ tile_e, const int* __restrict__ tile_m, const int* __restrict__ ntiles,
    float* __restrict__ out) {
  const int tile = blockIdx.x;
  if (tile >= *ntiles) return;
  const int e   = tile_e[tile];
  const int m0  = tile_m[tile];
  const int n0  = blockIdx.y * 128;
  const int Ne  = counts[e];
  const int seg = segoff[e];

  __shared__ bf16 As[128 * 64];
  __shared__ bf16 Bs[128 * 64];
  __shared__ int   sh_tok[128];
  __shared__ float sh_w[128];

  const int tid = threadIdx.x;
  const int lane = tid & 63;
  const int wv = tid >> 6;
  const int sr = tid >> 3;
  const int scb = tid & 7;

  if (tid < 128) {
    const int m = m0 + tid;
    if (m < Ne) { sh_tok[tid] = tokl[seg + m]; sh_w[tid] = wl[seg + m]; }
    else        { sh_tok[tid] = -1;            sh_w[tid] = 0.f; }
  }

  const bf16* aptr[4];
#pragma unroll
  for (int i = 0; i < 4; i++) {
    int m = m0 + sr + 32 * i; if (m > Ne - 1) m = Ne - 1;
    aptr[i] = act + (size_t)(seg + m) * HID + scb * 8;
  }
  const bf16* bptr[4];
#pragma unroll
  for (int i = 0; i < 4; i++) {
    const int d = n0 + sr + 32 * i;
    bptr[i] = w2b + ((size_t)e * DIM + d) * HID + scb * 8;
  }

  f32x16 acc[4];
#pragma unroll
  for (int i = 0; i < 4; i++)
#pragma unroll
    for (int j = 0; j < 16; j++) acc[i][j] = 0.f;

  const int lwm = (wv & 1) * 64;
  const int lwn = (wv >> 1) * 64;
  const int l31 = lane & 31;
  const int lhi = lane >> 5;

  for (int k0 = 0; k0 < HID; k0 += 64) {
#pragma unroll
    for (int i = 0; i < 4; i++)
      async_cp16(aptr[i] + k0, (char*)As + i * 4096 + tid * 16);
#pragma unroll
    for (int i = 0; i < 4; i++)
      async_cp16(bptr[i] + k0, (char*)Bs + i * 4096 + tid * 16);
    __syncthreads();
#pragma unroll
    for (int ks = 0; ks < 4; ks++) {
      const int kk = ks * 16 + lhi * 8;
      bf16x8 a0 = *(const bf16x8*)(As + (lwm + l31) * 64 + kk);
      bf16x8 a1 = *(const bf16x8*)(As + (lwm + 32 + l31) * 64 + kk);
      bf16x8 b0 = *(const bf16x8*)(Bs + (lwn + l31) * 64 + kk);
      bf16x8 b1 = *(const bf16x8*)(Bs + (lwn + 32 + l31) * 64 + kk);
      acc[0] = __builtin_amdgcn_mfma_f32_32x32x16_bf16(a0, b0, acc[0], 0, 0, 0);
      acc[1] = __builtin_amdgcn_mfma_f32_32x32x16_bf16(a0, b1, acc[1], 0, 0, 0);
      acc[2] = __builtin_amdgcn_mfma_f32_32x32x16_bf16(a1, b0, acc[2], 0, 0, 0);
      acc[3] = __builtin_amdgcn_mfma_f32_32x32x16_bf16(a1, b1, acc[3], 0, 0, 0);
    }
    __syncthreads();
  }

#pragma unroll
  for (int mi = 0; mi < 2; mi++) {
#pragma unroll
    for (int ni = 0; ni < 2; ni++) {
#pragma unroll
      for (int r = 0; r < 16; r++) {
        const int row = lwm + 32 * mi + (r & 3) + 8 * (r >> 2) + 4 * lhi;
        const int tok = sh_tok[row];
        if (tok >= 0) {
          const int col = n0 + lwn + 32 * ni + l31;
          atomicAdd(&out[(size_t)tok * DIM + col], sh_w[row] * acc[mi * 2 + ni][r]);
        }
      }
    }
  }
}

// ---------------- launch ----------------
extern "C" void kernel_launch(void* const* d_in, const int* in_sizes, int n_in,
                              void* d_out, int out_size, void* d_ws, size_t ws_size,
                              hipStream_t stream) {
  const float* x  = (const float*)d_in[0];
  const float* gw = (const float*)d_in[1];
  const float* w1 = (const float*)d_in[2];
  const float* w3 = (const float*)d_in[3];
  const float* w2 = (const float*)d_in[4];
  float* out = (float*)d_out;

  char* ws = (char*)d_ws;
  size_t off = 0;
  auto alloc = [&](size_t bytes) -> char* {
    char* p = ws + off; off += (bytes + 255) & ~(size_t)255; return p;
  };

  // --- small control buffers FIRST (so big-buffer sizing can't clobber them)
  int* ctrl = (int*)alloc(4096);        // 1024 ints
  int* counts = ctrl;                   // [0..7]
  int* fill   = ctrl + 8;               // [8..15]
  int* segoff = ctrl + 16;              // [16..24]
  int* ntiles = ctrl + 32;              // [32]
  int* tile_e = ctrl + 64;              // [64..327]   (<=264 entries)
  int* tile_m = ctrl + 512;             // [512..775]
  int*   sel  = (int*)alloc((size_t)T_TOK * 2 * 4);          // 128 KiB
  float* selw = (float*)alloc((size_t)T_TOK * 2 * 4);        // 128 KiB
  int*   tokl = (int*)alloc((size_t)2 * T_TOK * 4);          // 128 KiB
  float* wl   = (float*)alloc((size_t)2 * T_TOK * 4);        // 128 KiB

  // --- big buffers: 128 + 32 + 32 + 32 = 224 MiB total
  bf16* act  = (bf16*)alloc((size_t)2 * T_TOK * HID * 2);      // 128 MiB
  bf16* w1b  = (bf16*)alloc((size_t)NEXP * HID * DIM * 2);     // 32 MiB
  bf16* w3b  = (bf16*)alloc((size_t)NEXP * HID * DIM * 2);     // 32 MiB
  bf16* xb   = (bf16*)alloc((size_t)T_TOK * DIM * 2);          // 32 MiB
  bf16* w2b  = xb;   // ALIAS: xb dead after gemm_act; w2 converted after it
  (void)ws_size; (void)in_sizes; (void)n_in; (void)out_size;

  zero_kernel<<<T_TOK * DIM / 4 / 256, 256, 0, stream>>>((float4*)out, T_TOK * DIM / 4, ctrl);

  cvt_kernel<<<16384, 256, 0, stream>>>(x,  xb,  T_TOK * DIM / 4);
  cvt_kernel<<<16384, 256, 0, stream>>>(w1, w1b, NEXP * HID * DIM / 4);
  cvt_kernel<<<16384, 256, 0, stream>>>(w3, w3b, NEXP * HID * DIM / 4);

  gate_kernel<<<T_TOK, 64, 0, stream>>>(x, gw, sel, selw);
  count_kernel<<<2 * T_TOK / 256, 256, 0, stream>>>(sel, counts);
  tilemap_kernel<<<1, 64, 0, stream>>>(counts, segoff, tile_e, tile_m, ntiles);
  fill_kernel<<<T_TOK / 256, 256, 0, stream>>>(sel, selw, segoff, fill, tokl, wl);

  gemm_act_kernel<<<dim3(MAX_TILES, HID / 64), 256, 0, stream>>>(
      xb, w1b, w3b, tokl, counts, segoff, tile_e, tile_m, ntiles, act);

  cvt_kernel<<<16384, 256, 0, stream>>>(w2, w2b, NEXP * DIM * HID / 4);  // overwrites xb

  gemm_out_kernel<<<dim3(MAX_TILES, DIM / 128), 256, 0, stream>>>(
      act, w2b, tokl, wl, counts, segoff, tile_e, tile_m, ntiles, out);
}

// Round 3
// 1036.351 us; speedup vs baseline: 1.2023x; 1.2023x over previous
//
#include <hip/hip_runtime.h>
#include <hip/hip_bf16.h>
#include <cstdint>

// MoE SwiGLU: B=8 S=2048 D=1024 H=2048 E=8 K=2. T=16384 tokens.
// Routed (top-2 only) bf16-MFMA implementation; gating in fp32.
//
// R3: XOR-swizzled LDS layout. Row stride 64 bf16 = 128 B = 32 banks meant all
// 32 fragment lanes hit one 4-bank group (SQ_LDS_BANK_CONFLICT=2.4e8, 68% of
// cycles). Store (row, cb) at physical (row, cb ^ (row&7)): staging XORs the
// *global* column block (global_load_lds's LDS side must stay lane-ordered);
// reads XOR the column block. Also grid swapped so consecutive blocks share
// the A-tile (L2 reuse of gathered rows).

#define T_TOK 16384
#define DIM   1024
#define HID   2048
#define NEXP  8
#define MAX_TILES 264   // sum ceil(Ne/128) <= 32768/128 + 8

typedef __bf16 bf16;
typedef bf16  bf16x8 __attribute__((ext_vector_type(8)));
typedef bf16  bf16x4 __attribute__((ext_vector_type(4)));
typedef float f32x16 __attribute__((ext_vector_type(16)));

__device__ __forceinline__ void async_cp16(const void* g, void* l) {
  __builtin_amdgcn_global_load_lds((const __attribute__((address_space(1))) void*)g,
                                   (__attribute__((address_space(3))) void*)l, 16, 0, 0);
}

// ---------------- zero out + control ints ----------------
__global__ __launch_bounds__(256) void zero_kernel(float4* __restrict__ out4, int n4,
                                                   int* __restrict__ ctrl) {
  const int i = blockIdx.x * 256 + threadIdx.x;
  if (i < n4) out4[i] = float4{0.f, 0.f, 0.f, 0.f};
  if (blockIdx.x == 0 && threadIdx.x < 64) ctrl[threadIdx.x] = 0;
}

// ---------------- fp32 -> bf16 convert ----------------
__global__ __launch_bounds__(256) void cvt_kernel(const float* __restrict__ in,
                                                  bf16* __restrict__ out, int n4) {
  const int i = blockIdx.x * 256 + threadIdx.x;
  if (i < n4) {
    const float4 v = ((const float4*)in)[i];
    bf16x4 o;
    o[0] = (bf16)v.x; o[1] = (bf16)v.y; o[2] = (bf16)v.z; o[3] = (bf16)v.w;
    ((bf16x4*)out)[i] = o;
  }
}

// ---------------- gating: fp32 logits, top-2, softmax ----------------
__global__ __launch_bounds__(64) void gate_kernel(const float* __restrict__ x,
                                                  const float* __restrict__ gw,
                                                  int* __restrict__ sel,
                                                  float* __restrict__ selw) {
  const int t = blockIdx.x;
  const int lane = threadIdx.x;
  const float* xr = x + (size_t)t * DIM;
  float acc[NEXP];
#pragma unroll
  for (int e = 0; e < NEXP; e++) acc[e] = 0.f;
  for (int i = lane; i < DIM; i += 64) {
    const float xv = xr[i];
#pragma unroll
    for (int e = 0; e < NEXP; e++) acc[e] += xv * gw[e * DIM + i];
  }
#pragma unroll
  for (int e = 0; e < NEXP; e++) {
#pragma unroll
    for (int m = 1; m < 64; m <<= 1) acc[e] += __shfl_xor(acc[e], m);
  }
  if (lane == 0) {
    int e0 = 0; float l0 = acc[0];
#pragma unroll
    for (int e = 1; e < NEXP; e++) if (acc[e] > l0) { l0 = acc[e]; e0 = e; }
    int e1 = -1; float l1 = -3.4e38f;
#pragma unroll
    for (int e = 0; e < NEXP; e++) if (e != e0 && acc[e] > l1) { l1 = acc[e]; e1 = e; }
    const float ex = expf(l1 - l0);            // l1 <= l0
    const float w0 = 1.f / (1.f + ex);
    sel[t * 2] = e0;  sel[t * 2 + 1] = e1;
    selw[t * 2] = w0; selw[t * 2 + 1] = 1.f - w0;
  }
}

// ---------------- per-expert counts ----------------
__global__ __launch_bounds__(256) void count_kernel(const int* __restrict__ sel,
                                                    int* __restrict__ counts) {
  const int i = blockIdx.x * 256 + threadIdx.x;
  const int lane = threadIdx.x & 63;
  const int e = sel[i];
#pragma unroll
  for (int ee = 0; ee < NEXP; ee++) {
    const unsigned long long mask = __ballot(e == ee);
    if (e == ee) {
      const int leader = __ffsll(mask) - 1;
      if (lane == leader) atomicAdd(&counts[ee], __popcll(mask));
    }
  }
}

// ---------------- segment offsets + tile map ----------------
__global__ void tilemap_kernel(const int* __restrict__ counts, int* __restrict__ segoff,
                               int* __restrict__ tile_e, int* __restrict__ tile_m,
                               int* __restrict__ ntiles) {
  if (threadIdx.x == 0 && blockIdx.x == 0) {
    int off = 0, nt = 0;
    for (int e = 0; e < NEXP; e++) {
      segoff[e] = off;
      const int c = counts[e];
      for (int m = 0; m < c; m += 128) { tile_e[nt] = e; tile_m[nt] = m; nt++; }
      off += c;
    }
    segoff[NEXP] = off;
    ntiles[0] = nt;
  }
}

// ---------------- fill gather lists ----------------
__global__ __launch_bounds__(256) void fill_kernel(const int* __restrict__ sel,
                                                   const float* __restrict__ selw,
                                                   const int* __restrict__ segoff,
                                                   int* __restrict__ fill,
                                                   int* __restrict__ tokl,
                                                   float* __restrict__ wl) {
  const int t = blockIdx.x * 256 + threadIdx.x;
  const int lane = threadIdx.x & 63;
#pragma unroll
  for (int s = 0; s < 2; s++) {
    const int e = sel[t * 2 + s];
    const float w = selw[t * 2 + s];
    for (int ee = 0; ee < NEXP; ee++) {
      const unsigned long long mask = __ballot(e == ee);
      if (e == ee) {
        const int leader = __ffsll(mask) - 1;
        const int cnt = __popcll(mask);
        int base = 0;
        if (lane == leader) base = atomicAdd(&fill[ee], cnt);
        base = __shfl(base, leader);
        const int pos = base + __popcll(mask & ((1ull << lane) - 1ull));
        const int idx = segoff[ee] + pos;
        tokl[idx] = t;
        wl[idx] = w;
      }
    }
  }
}

// ---------------- GEMM1 + SwiGLU: act = silu(Xe@w1^T) * (Xe@w3^T) ----------------
// BM=128, BN=64, BK=64. XOR-swizzled LDS: logical (row, cb) at physical
// (row, cb^(row&7)); 16B blocks. mfma_f32_32x32x16_bf16, C/D:
// col=lane&31, row=(reg&3)+8*(reg>>2)+4*(lane>>5).
__global__ __launch_bounds__(256) void gemm_act_kernel(
    const bf16* __restrict__ xb, const bf16* __restrict__ w1b, const bf16* __restrict__ w3b,
    const int* __restrict__ tokl, const int* __restrict__ counts, const int* __restrict__ segoff,
    const int* __restrict__ tile_e, const int* __restrict__ tile_m, const int* __restrict__ ntiles,
    bf16* __restrict__ act) {
  const int tile = blockIdx.y;
  if (tile >= *ntiles) return;
  const int e   = tile_e[tile];
  const int m0  = tile_m[tile];
  const int n0  = blockIdx.x * 64;
  const int Ne  = counts[e];
  const int seg = segoff[e];

  __shared__ bf16 As[128 * 64];
  __shared__ bf16 Bs1[64 * 64];
  __shared__ bf16 Bs3[64 * 64];

  const int tid = threadIdx.x;
  const int lane = tid & 63;
  const int wv = tid >> 6;
  const int sr = tid >> 3;               // staging row 0..31
  const int scb = (tid & 7) ^ (sr & 7);  // SWIZZLE: global col block for this lane's slot

  const bf16* aptr[4];
#pragma unroll
  for (int i = 0; i < 4; i++) {
    int m = m0 + sr + 32 * i; if (m > Ne - 1) m = Ne - 1;   // clamp tail
    aptr[i] = xb + (size_t)tokl[seg + m] * DIM + scb * 8;
  }
  const bf16 *b1p[2], *b3p[2];
#pragma unroll
  for (int i = 0; i < 2; i++) {
    const int n = n0 + sr + 32 * i;
    b1p[i] = w1b + ((size_t)e * HID + n) * DIM + scb * 8;
    b3p[i] = w3b + ((size_t)e * HID + n) * DIM + scb * 8;
  }

  f32x16 acc1[2], acc3[2];
#pragma unroll
  for (int i = 0; i < 2; i++)
#pragma unroll
    for (int j = 0; j < 16; j++) { acc1[i][j] = 0.f; acc3[i][j] = 0.f; }

  const int lwm = (wv & 1) * 64;
  const int lwn = (wv >> 1) * 32;
  const int l31 = lane & 31;
  const int lhi = lane >> 5;
  const int l7  = l31 & 7;

  for (int k0 = 0; k0 < DIM; k0 += 64) {
#pragma unroll
    for (int i = 0; i < 4; i++)
      async_cp16(aptr[i] + k0, (char*)As + i * 4096 + tid * 16);
#pragma unroll
    for (int i = 0; i < 2; i++) {
      async_cp16(b1p[i] + k0, (char*)Bs1 + i * 4096 + tid * 16);
      async_cp16(b3p[i] + k0, (char*)Bs3 + i * 4096 + tid * 16);
    }
    __syncthreads();
#pragma unroll
    for (int ks = 0; ks < 4; ks++) {
      const int swz = (((ks * 2 + lhi) ^ l7) * 8);   // swizzled col offset (elems)
      bf16x8 a0 = *(const bf16x8*)(As + (lwm + l31) * 64 + swz);
      bf16x8 a1 = *(const bf16x8*)(As + (lwm + 32 + l31) * 64 + swz);
      bf16x8 b1 = *(const bf16x8*)(Bs1 + (lwn + l31) * 64 + swz);
      bf16x8 b3 = *(const bf16x8*)(Bs3 + (lwn + l31) * 64 + swz);
      acc1[0] = __builtin_amdgcn_mfma_f32_32x32x16_bf16(a0, b1, acc1[0], 0, 0, 0);
      acc3[0] = __builtin_amdgcn_mfma_f32_32x32x16_bf16(a0, b3, acc3[0], 0, 0, 0);
      acc1[1] = __builtin_amdgcn_mfma_f32_32x32x16_bf16(a1, b1, acc1[1], 0, 0, 0);
      acc3[1] = __builtin_amdgcn_mfma_f32_32x32x16_bf16(a1, b3, acc3[1], 0, 0, 0);
    }
    __syncthreads();
  }

#pragma unroll
  for (int ms = 0; ms < 2; ms++) {
#pragma unroll
    for (int r = 0; r < 16; r++) {
      const int row = lwm + 32 * ms + (r & 3) + 8 * (r >> 2) + 4 * lhi;
      const int m = m0 + row;
      if (m < Ne) {
        const float h1 = acc1[ms][r];
        const float h3 = acc3[ms][r];
        const float sv = h1 / (1.f + __expf(-h1)) * h3;
        act[(size_t)(seg + m) * HID + (n0 + lwn + l31)] = (bf16)sv;
      }
    }
  }
}

// ---------------- GEMM2 + scatter: out[tok] += cw * (act @ w2^T) ----------------
// BM=128, BN=128, BK=64. Same XOR swizzle.
__global__ __launch_bounds__(256) void gemm_out_kernel(
    const bf16* __restrict__ act, const bf16* __restrict__ w2b,
    const int* __restrict__ tokl, const float* __restrict__ wl,
    const int* __restrict__ counts, const int* __restrict__ segoff,
    const int* __restrict__ tile_e, const int* __restrict__ tile_m, const int* __restrict__ ntiles,
    float* __restrict__ out) {
  const int tile = blockIdx.y;
  if (tile >= *ntiles) return;
  const int e   = tile_e[tile];
  const int m0  = tile_m[tile];
  const int n0  = blockIdx.x * 128;
  const int Ne  = counts[e];
  const int seg = segoff[e];

  __shared__ bf16 As[128 * 64];
  __shared__ bf16 Bs[128 * 64];
  __shared__ int   sh_tok[128];
  __shared__ float sh_w[128];

  const int tid = threadIdx.x;
  const int lane = tid & 63;
  const int wv = tid >> 6;
  const int sr = tid >> 3;
  const int scb = (tid & 7) ^ (sr & 7);  // SWIZZLE

  if (tid < 128) {
    const int m = m0 + tid;
    if (m < Ne) { sh_tok[tid] = tokl[seg + m]; sh_w[tid] = wl[seg + m]; }
    else        { sh_tok[tid] = -1;            sh_w[tid] = 0.f; }
  }

  const bf16* aptr[4];
#pragma unroll
  for (int i = 0; i < 4; i++) {
    int m = m0 + sr + 32 * i; if (m > Ne - 1) m = Ne - 1;
    aptr[i] = act + (size_t)(seg + m) * HID + scb * 8;
  }
  const bf16* bptr[4];
#pragma unroll
  for (int i = 0; i < 4; i++) {
    const int d = n0 + sr + 32 * i;
    bptr[i] = w2b + ((size_t)e * DIM + d) * HID + scb * 8;
  }

  f32x16 acc[4];
#pragma unroll
  for (int i = 0; i < 4; i++)
#pragma unroll
    for (int j = 0; j < 16; j++) acc[i][j] = 0.f;

  const int lwm = (wv & 1) * 64;
  const int lwn = (wv >> 1) * 64;
  const int l31 = lane & 31;
  const int lhi = lane >> 5;
  const int l7  = l31 & 7;

  for (int k0 = 0; k0 < HID; k0 += 64) {
#pragma unroll
    for (int i = 0; i < 4; i++)
      async_cp16(aptr[i] + k0, (char*)As + i * 4096 + tid * 16);
#pragma unroll
    for (int i = 0; i < 4; i++)
      async_cp16(bptr[i] + k0, (char*)Bs + i * 4096 + tid * 16);
    __syncthreads();
#pragma unroll
    for (int ks = 0; ks < 4; ks++) {
      const int swz = (((ks * 2 + lhi) ^ l7) * 8);
      bf16x8 a0 = *(const bf16x8*)(As + (lwm + l31) * 64 + swz);
      bf16x8 a1 = *(const bf16x8*)(As + (lwm + 32 + l31) * 64 + swz);
      bf16x8 b0 = *(const bf16x8*)(Bs + (lwn + l31) * 64 + swz);
      bf16x8 b1 = *(const bf16x8*)(Bs + (lwn + 32 + l31) * 64 + swz);
      acc[0] = __builtin_amdgcn_mfma_f32_32x32x16_bf16(a0, b0, acc[0], 0, 0, 0);
      acc[1] = __builtin_amdgcn_mfma_f32_32x32x16_bf16(a0, b1, acc[1], 0, 0, 0);
      acc[2] = __builtin_amdgcn_mfma_f32_32x32x16_bf16(a1, b0, acc[2], 0, 0, 0);
      acc[3] = __builtin_amdgcn_mfma_f32_32x32x16_bf16(a1, b1, acc[3], 0, 0, 0);
    }
    __syncthreads();
  }

#pragma unroll
  for (int mi = 0; mi < 2; mi++) {
#pragma unroll
    for (int ni = 0; ni < 2; ni++) {
#pragma unroll
      for (int r = 0; r < 16; r++) {
        const int row = lwm + 32 * mi + (r & 3) + 8 * (r >> 2) + 4 * lhi;
        const int tok = sh_tok[row];
        if (tok >= 0) {
          const int col = n0 + lwn + 32 * ni + l31;
          atomicAdd(&out[(size_t)tok * DIM + col], sh_w[row] * acc[mi * 2 + ni][r]);
        }
      }
    }
  }
}

// ---------------- launch ----------------
extern "C" void kernel_launch(void* const* d_in, const int* in_sizes, int n_in,
                              void* d_out, int out_size, void* d_ws, size_t ws_size,
                              hipStream_t stream) {
  const float* x  = (const float*)d_in[0];
  const float* gw = (const float*)d_in[1];
  const float* w1 = (const float*)d_in[2];
  const float* w3 = (const float*)d_in[3];
  const float* w2 = (const float*)d_in[4];
  float* out = (float*)d_out;

  char* ws = (char*)d_ws;
  size_t off = 0;
  auto alloc = [&](size_t bytes) -> char* {
    char* p = ws + off; off += (bytes + 255) & ~(size_t)255; return p;
  };

  // --- small control buffers FIRST
  int* ctrl = (int*)alloc(4096);
  int* counts = ctrl;                   // [0..7]
  int* fill   = ctrl + 8;               // [8..15]
  int* segoff = ctrl + 16;              // [16..24]
  int* ntiles = ctrl + 32;              // [32]
  int* tile_e = ctrl + 64;              // [64..327]
  int* tile_m = ctrl + 512;             // [512..775]
  int*   sel  = (int*)alloc((size_t)T_TOK * 2 * 4);
  float* selw = (float*)alloc((size_t)T_TOK * 2 * 4);
  int*   tokl = (int*)alloc((size_t)2 * T_TOK * 4);
  float* wl   = (float*)alloc((size_t)2 * T_TOK * 4);

  // --- big buffers: 128 + 32 + 32 + 32 = 224 MiB
  bf16* act  = (bf16*)alloc((size_t)2 * T_TOK * HID * 2);      // 128 MiB
  bf16* w1b  = (bf16*)alloc((size_t)NEXP * HID * DIM * 2);     // 32 MiB
  bf16* w3b  = (bf16*)alloc((size_t)NEXP * HID * DIM * 2);     // 32 MiB
  bf16* xb   = (bf16*)alloc((size_t)T_TOK * DIM * 2);          // 32 MiB
  bf16* w2b  = xb;   // ALIAS: xb dead after gemm_act
  (void)ws_size; (void)in_sizes; (void)n_in; (void)out_size;

  zero_kernel<<<T_TOK * DIM / 4 / 256, 256, 0, stream>>>((float4*)out, T_TOK * DIM / 4, ctrl);

  cvt_kernel<<<16384, 256, 0, stream>>>(x,  xb,  T_TOK * DIM / 4);
  cvt_kernel<<<16384, 256, 0, stream>>>(w1, w1b, NEXP * HID * DIM / 4);
  cvt_kernel<<<16384, 256, 0, stream>>>(w3, w3b, NEXP * HID * DIM / 4);

  gate_kernel<<<T_TOK, 64, 0, stream>>>(x, gw, sel, selw);
  count_kernel<<<2 * T_TOK / 256, 256, 0, stream>>>(sel, counts);
  tilemap_kernel<<<1, 64, 0, stream>>>(counts, segoff, tile_e, tile_m, ntiles);
  fill_kernel<<<T_TOK / 256, 256, 0, stream>>>(sel, selw, segoff, fill, tokl, wl);

  gemm_act_kernel<<<dim3(HID / 64, MAX_TILES), 256, 0, stream>>>(
      xb, w1b, w3b, tokl, counts, segoff, tile_e, tile_m, ntiles, act);

  cvt_kernel<<<16384, 256, 0, stream>>>(w2, w2b, NEXP * DIM * HID / 4);  // overwrites xb

  gemm_out_kernel<<<dim3(DIM / 128, MAX_TILES), 256, 0, stream>>>(
      act, w2b, tokl, wl, counts, segoff, tile_e, tile_m, ntiles, out);
}